// Round 8
// baseline (982.342 us; speedup 1.0000x reference)
//
#include <hip/hip_runtime.h>
#include <math.h>

#define B 2
#define S 2048
#define D 2048
#define H 32
#define HD 64
#define M (B*S)

typedef short s16x8 __attribute__((ext_vector_type(8)));
typedef float f32x4 __attribute__((ext_vector_type(4)));

// fp32 -> bf16 (RNE) and back, pure bit ops
__device__ __forceinline__ unsigned short f2bf(float f) {
    unsigned u = __float_as_uint(f);
    return (unsigned short)((u + 0x7fffu + ((u >> 16) & 1u)) >> 16);
}
__device__ __forceinline__ float bf2f(unsigned short h) {
    return __uint_as_float(((unsigned)h) << 16);
}

// ---------------------------------------------------------------------------
// split: fp32 array -> hi/lo bf16 arrays (hoists conversion out of GEMM loop)
// ---------------------------------------------------------------------------
__global__ __launch_bounds__(256) void split_kernel(
    const float* __restrict__ in, unsigned short* __restrict__ hi,
    unsigned short* __restrict__ lo, int n)
{
    const int idx = (blockIdx.x * 256 + threadIdx.x) * 8;
    if (idx >= n) return;
    float f[8];
    *(float4*)&f[0] = *(const float4*)(in + idx);
    *(float4*)&f[4] = *(const float4*)(in + idx + 4);
    unsigned short h[8], l[8];
    #pragma unroll
    for (int e = 0; e < 8; ++e) {
        h[e] = f2bf(f[e]);
        l[e] = f2bf(f[e] - bf2f(h[e]));
    }
    *(s16x8*)&hi[idx] = *(s16x8*)&h[0];
    *(s16x8*)&lo[idx] = *(s16x8*)&l[0];
}

// ---------------------------------------------------------------------------
// bf16x3 MFMA GEMM on PRE-SPLIT inputs: C = A[M,K] * Bw[N,K]^T
// C = Ah*Bh + Ah*Bl + Al*Bh. Staging = pure short8 copies (no VALU convert).
// Output: fp32 (Cf) and/or bf16 hi/lo (Ch, Cl) — uniform runtime branches.
// Structure (tile/LDS/frags/C-map) identical to the verified gemm_bf16x3.
// ---------------------------------------------------------------------------
#define GBM 128
#define GBN 128
#define GBK 32
#define GLD (GBK + 8)

__global__ __launch_bounds__(256) void gemm_pre(
    const unsigned short* __restrict__ Agh, const unsigned short* __restrict__ Agl,
    const unsigned short* __restrict__ Bgh, const unsigned short* __restrict__ Bgl,
    float* __restrict__ Cf, unsigned short* __restrict__ Ch,
    unsigned short* __restrict__ Cl, int Ndim, int Kdim)
{
    __shared__ unsigned short Ah[GBM * GLD], Al[GBM * GLD];
    __shared__ unsigned short Bh[GBN * GLD], Bl[GBN * GLD];
    const int tid = threadIdx.x;
    const int nwg = gridDim.x, cpx = nwg >> 3;
    const int wg = (blockIdx.x & 7) * cpx + (blockIdx.x >> 3);
    const int ntn = Ndim / GBN;
    const int m0 = (wg / ntn) * GBM, n0 = (wg % ntn) * GBN;

    const int row = tid >> 1;            // 0..127
    const int seg = (tid & 1) << 4;      // 0 or 16 shorts
    const size_t abase = (size_t)(m0 + row) * Kdim + seg;
    const size_t bbase = (size_t)(n0 + row) * Kdim + seg;
    const int sbase = row * GLD + seg;

    const int wv = tid >> 6, lane = tid & 63;
    const int wr = (wv >> 1) << 6, wc = (wv & 1) << 6;
    const int fr = lane & 15, ko = (lane >> 4) << 3;

    f32x4 acc[4][4] = {};
    for (int k0 = 0; k0 < Kdim; k0 += GBK) {
        *(s16x8*)&Ah[sbase]     = *(const s16x8*)&Agh[abase + k0];
        *(s16x8*)&Ah[sbase + 8] = *(const s16x8*)&Agh[abase + k0 + 8];
        *(s16x8*)&Al[sbase]     = *(const s16x8*)&Agl[abase + k0];
        *(s16x8*)&Al[sbase + 8] = *(const s16x8*)&Agl[abase + k0 + 8];
        *(s16x8*)&Bh[sbase]     = *(const s16x8*)&Bgh[bbase + k0];
        *(s16x8*)&Bh[sbase + 8] = *(const s16x8*)&Bgh[bbase + k0 + 8];
        *(s16x8*)&Bl[sbase]     = *(const s16x8*)&Bgl[bbase + k0];
        *(s16x8*)&Bl[sbase + 8] = *(const s16x8*)&Bgl[bbase + k0 + 8];
        __syncthreads();
        s16x8 fah[4], fal[4], fbh[4], fbl[4];
        #pragma unroll
        for (int m = 0; m < 4; ++m) {
            const int r = (wr + m * 16 + fr) * GLD + ko;
            fah[m] = *(s16x8*)&Ah[r];
            fal[m] = *(s16x8*)&Al[r];
        }
        #pragma unroll
        for (int n = 0; n < 4; ++n) {
            const int r = (wc + n * 16 + fr) * GLD + ko;
            fbh[n] = *(s16x8*)&Bh[r];
            fbl[n] = *(s16x8*)&Bl[r];
        }
        #pragma unroll
        for (int m = 0; m < 4; ++m)
            #pragma unroll
            for (int n = 0; n < 4; ++n) {
                acc[m][n] = __builtin_amdgcn_mfma_f32_16x16x32_bf16(fah[m], fbh[n], acc[m][n], 0, 0, 0);
                acc[m][n] = __builtin_amdgcn_mfma_f32_16x16x32_bf16(fah[m], fbl[n], acc[m][n], 0, 0, 0);
                acc[m][n] = __builtin_amdgcn_mfma_f32_16x16x32_bf16(fal[m], fbh[n], acc[m][n], 0, 0, 0);
            }
        __syncthreads();
    }
    const int crow0 = m0 + wr + ((lane >> 4) << 2);
    const int ccol0 = n0 + wc + fr;
    #pragma unroll
    for (int m = 0; m < 4; ++m)
        #pragma unroll
        for (int n = 0; n < 4; ++n)
            #pragma unroll
            for (int r = 0; r < 4; ++r) {
                const float c = acc[m][n][r];
                const size_t idx = (size_t)(crow0 + m * 16 + r) * Ndim + ccol0 + n * 16;
                if (Cf) Cf[idx] = c;
                if (Ch) {
                    const unsigned short hh = f2bf(c);
                    Ch[idx] = hh;
                    if (Cl) Cl[idx] = f2bf(c - bf2f(hh));
                }
            }
}

// ---------------------------------------------------------------------------
// Forget gates + cumsum (unchanged, verified)
// ---------------------------------------------------------------------------
__global__ __launch_bounds__(256) void fgate_kernel(
    const float* __restrict__ x, const float* __restrict__ Wf,
    const float* __restrict__ bfv, float* __restrict__ F)
{
    __shared__ float xs[D];
    const int bs = blockIdx.x;
    const float* xr = x + (size_t)bs * D;
    for (int i = threadIdx.x * 4; i < D; i += 256 * 4)
        *(float4*)&xs[i] = *(const float4*)&xr[i];
    __syncthreads();
    const int wave = threadIdx.x >> 6, lane = threadIdx.x & 63;
    for (int h = wave * 8; h < wave * 8 + 8; ++h) {
        const float* wr = Wf + (size_t)h * D;
        float sum = 0.f;
        for (int i = lane * 4; i < D; i += 64 * 4) {
            float4 w4 = *(const float4*)&wr[i];
            sum += xs[i]*w4.x + xs[i+1]*w4.y + xs[i+2]*w4.z + xs[i+3]*w4.w;
        }
        #pragma unroll
        for (int off = 32; off > 0; off >>= 1) sum += __shfl_down(sum, off);
        if (lane == 0) {
            float z = sum + bfv[h];
            F[(size_t)bs * H + h] = fminf(z, 0.f) - log1pf(expf(-fabsf(z)));
        }
    }
}

__global__ __launch_bounds__(256) void cumsum_kernel(float* __restrict__ F)
{
    const int b = blockIdx.x >> 5;
    const int h = blockIdx.x & 31;
    float* base = F + (size_t)b * S * H + h;
    __shared__ float part[256];
    const int t = threadIdx.x;
    float v[8];
    float run = 0.f;
    #pragma unroll
    for (int i = 0; i < 8; ++i) {
        v[i] = base[(size_t)(t * 8 + i) * H];
        run += v[i];
        v[i] = run;
    }
    part[t] = run;
    __syncthreads();
    for (int off = 1; off < 256; off <<= 1) {
        float add = (t >= off) ? part[t - off] : 0.f;
        __syncthreads();
        part[t] += add;
        __syncthreads();
    }
    const float offs = (t > 0) ? part[t - 1] : 0.f;
    #pragma unroll
    for (int i = 0; i < 8; ++i)
        base[(size_t)(t * 8 + i) * H] = v[i] + offs;
}

// ---------------------------------------------------------------------------
// MFMA flash attention v2: bf16 inputs (pre-split Q hi/lo, K/V hi).
// Q frags load DIRECTLY global->registers (read-once; no LDS staging)
// => LDS 37 KB => 4 blocks/CU (2x occupancy vs v1).
// Output written as bf16 hi/lo (feeds the out-projection GEMM directly).
// ---------------------------------------------------------------------------
#define QBLK 128
#define KV 64
#define PLD 72
#define SCALE 0.125f    // 1/sqrt(64)

__global__ __launch_bounds__(256, 4) void attn_mfma2(
    const unsigned short* __restrict__ Qh, const unsigned short* __restrict__ Ql,
    const unsigned short* __restrict__ Kh, const unsigned short* __restrict__ Vh,
    const float* __restrict__ C,
    unsigned short* __restrict__ Oh, unsigned short* __restrict__ Ol)
{
    __shared__ unsigned short Ks[KV * PLD];
    __shared__ unsigned short Vt[HD * PLD];
    __shared__ unsigned short Pb[4 * 32 * PLD];
    __shared__ float cj[KV];

    const int qt = (int)gridDim.x - 1 - blockIdx.x;
    const int b = blockIdx.z >> 5, h = blockIdx.z & 31;
    const int q0 = qt * QBLK;
    const int tid = threadIdx.x, wv = tid >> 6, lane = tid & 63;
    const int g = lane >> 4, fr = lane & 15;

    // ---- Q fragments: direct global -> registers (once) ----
    s16x8 qfh[2][2], qfl[2][2];   // [m][kd]
    {
        const size_t qb = (size_t)(b * S + q0 + wv * 32) * D + h * HD;
        #pragma unroll
        for (int m = 0; m < 2; ++m)
            #pragma unroll
            for (int kd = 0; kd < 2; ++kd) {
                const size_t off = qb + (size_t)(m * 16 + fr) * D + kd * 32 + g * 8;
                qfh[m][kd] = *(const s16x8*)&Qh[off];
                qfl[m][kd] = *(const s16x8*)&Ql[off];
            }
    }

    f32x4 Oa[2][4] = {};
    float mr[2][4], lr[2][4];
    #pragma unroll
    for (int m = 0; m < 2; ++m)
        #pragma unroll
        for (int r = 0; r < 4; ++r) { mr[m][r] = -INFINITY; lr[m][r] = 0.f; }

    const int imax = q0 + wv * 32 + 31;
    const int nj = (q0 + QBLK) / KV;
    unsigned short* Pw = &Pb[wv * 32 * PLD];

    for (int jt = 0; jt < nj; ++jt) {
        const int j0 = jt * KV;
        // ---- stage K (row-major) and V (transposed) from bf16 ----
        {
            const int row = tid >> 2;            // 0..63 (j)
            const int seg = (tid & 3) << 4;      // 0,16,32,48 (d, shorts)
            const size_t goff = (size_t)(b * S + j0 + row) * D + h * HD + seg;
            *(s16x8*)&Ks[row * PLD + seg]     = *(const s16x8*)&Kh[goff];
            *(s16x8*)&Ks[row * PLD + seg + 8] = *(const s16x8*)&Kh[goff + 8];
            s16x8 v0 = *(const s16x8*)&Vh[goff];
            s16x8 v1 = *(const s16x8*)&Vh[goff + 8];
            #pragma unroll
            for (int e = 0; e < 8; ++e) {
                Vt[(seg + e) * PLD + row]     = (unsigned short)v0[e];
                Vt[(seg + 8 + e) * PLD + row] = (unsigned short)v1[e];
            }
            if (tid < KV)
                cj[tid] = C[(size_t)(b * S + j0 + tid) * H + h];
        }
        __syncthreads();

        if (j0 <= imax) {
            // ---- QK^T (hi + lo) ----
            s16x8 kfr[4][2];
            #pragma unroll
            for (int n = 0; n < 4; ++n)
                #pragma unroll
                for (int kd = 0; kd < 2; ++kd)
                    kfr[n][kd] = *(s16x8*)&Ks[(n * 16 + fr) * PLD + kd * 32 + g * 8];
            f32x4 sa[2][4] = {};
            #pragma unroll
            for (int m = 0; m < 2; ++m)
                #pragma unroll
                for (int n = 0; n < 4; ++n) {
                    #pragma unroll
                    for (int kd = 0; kd < 2; ++kd) {
                        sa[m][n] = __builtin_amdgcn_mfma_f32_16x16x32_bf16(qfh[m][kd], kfr[n][kd], sa[m][n], 0, 0, 0);
                        sa[m][n] = __builtin_amdgcn_mfma_f32_16x16x32_bf16(qfl[m][kd], kfr[n][kd], sa[m][n], 0, 0, 0);
                    }
                }
            // ---- scores ----
            float cjr[4];
            #pragma unroll
            for (int n = 0; n < 4; ++n) cjr[n] = cj[fr + 16 * n];
            float sc[2][4][4];
            float tm[2][4];
            #pragma unroll
            for (int m = 0; m < 2; ++m)
                #pragma unroll
                for (int r = 0; r < 4; ++r) tm[m][r] = -INFINITY;
            #pragma unroll
            for (int m = 0; m < 2; ++m)
                #pragma unroll
                for (int n = 0; n < 4; ++n)
                    #pragma unroll
                    for (int r = 0; r < 4; ++r) {
                        const int qrow = q0 + wv * 32 + m * 16 + g * 4 + r;
                        const int jcol = j0 + fr + 16 * n;
                        float s = sa[m][n][r] * SCALE - cjr[n];
                        s = (jcol <= qrow) ? s : -INFINITY;
                        sc[m][n][r] = s;
                        tm[m][r] = fmaxf(tm[m][r], s);
                    }
            #pragma unroll
            for (int m = 0; m < 2; ++m)
                #pragma unroll
                for (int r = 0; r < 4; ++r) {
                    float v = tm[m][r];
                    v = fmaxf(v, __shfl_xor(v, 1));
                    v = fmaxf(v, __shfl_xor(v, 2));
                    v = fmaxf(v, __shfl_xor(v, 4));
                    v = fmaxf(v, __shfl_xor(v, 8));
                    tm[m][r] = v;
                }
            #pragma unroll
            for (int m = 0; m < 2; ++m)
                #pragma unroll
                for (int r = 0; r < 4; ++r) {
                    const float newm = fmaxf(mr[m][r], tm[m][r]);
                    const float corr = __expf(mr[m][r] - newm);
                    mr[m][r] = newm;
                    lr[m][r] *= corr;
                    #pragma unroll
                    for (int n = 0; n < 4; ++n) Oa[m][n][r] *= corr;
                }
            #pragma unroll
            for (int m = 0; m < 2; ++m) {
                float ps[4];
                #pragma unroll
                for (int r = 0; r < 4; ++r) ps[r] = 0.f;
                #pragma unroll
                for (int n = 0; n < 4; ++n)
                    #pragma unroll
                    for (int r = 0; r < 4; ++r) {
                        const float p = __expf(sc[m][n][r] - mr[m][r]);
                        ps[r] += p;
                        Pw[(m * 16 + g * 4 + r) * PLD + fr + 16 * n] = f2bf(p);
                    }
                #pragma unroll
                for (int r = 0; r < 4; ++r) {
                    float v = ps[r];
                    v += __shfl_xor(v, 1);
                    v += __shfl_xor(v, 2);
                    v += __shfl_xor(v, 4);
                    v += __shfl_xor(v, 8);
                    lr[m][r] += v;
                }
            }
            // ---- PV ----
            s16x8 pf[2][2], vfr[4][2];
            #pragma unroll
            for (int m = 0; m < 2; ++m)
                #pragma unroll
                for (int kj = 0; kj < 2; ++kj)
                    pf[m][kj] = *(s16x8*)&Pw[(fr + 16 * m) * PLD + kj * 32 + g * 8];
            #pragma unroll
            for (int n = 0; n < 4; ++n)
                #pragma unroll
                for (int kj = 0; kj < 2; ++kj)
                    vfr[n][kj] = *(s16x8*)&Vt[(n * 16 + fr) * PLD + kj * 32 + g * 8];
            #pragma unroll
            for (int m = 0; m < 2; ++m)
                #pragma unroll
                for (int n = 0; n < 4; ++n)
                    #pragma unroll
                    for (int kj = 0; kj < 2; ++kj)
                        Oa[m][n] = __builtin_amdgcn_mfma_f32_16x16x32_bf16(pf[m][kj], vfr[n][kj], Oa[m][n], 0, 0, 0);
        }
        __syncthreads();
    }

    // ---- normalize + store as bf16 hi/lo ----
    #pragma unroll
    for (int m = 0; m < 2; ++m)
        #pragma unroll
        for (int r = 0; r < 4; ++r) {
            const float inv = 1.f / lr[m][r];
            const size_t rowb = (size_t)(b * S + q0 + wv * 32 + m * 16 + g * 4 + r) * D + h * HD;
            #pragma unroll
            for (int n = 0; n < 4; ++n) {
                const float c = Oa[m][n][r] * inv;
                const unsigned short hh = f2bf(c);
                Oh[rowb + fr + 16 * n] = hh;
                Ol[rowb + fr + 16 * n] = f2bf(c - bf2f(hh));
            }
        }
}

// ---------------------------------------------------------------------------
extern "C" void kernel_launch(void* const* d_in, const int* in_sizes, int n_in,
                              void* d_out, int out_size, void* d_ws, size_t ws_size,
                              hipStream_t stream) {
    const float* x  = (const float*)d_in[0];
    const float* Wq = (const float*)d_in[1];
    const float* Wk = (const float*)d_in[2];
    const float* Wv = (const float*)d_in[3];
    const float* Wf = (const float*)d_in[4];
    const float* bf = (const float*)d_in[5];
    const float* Wo = (const float*)d_in[6];
    float* out = (float*)d_out;

    const size_t MD = (size_t)M * D, DD = (size_t)D * D;
    // ws layout (shorts): Xh | Xl | Wh | Wl | Qh | Ql | Kh | Vh | Fc(fp32)
    // Oh/Ol alias Xh/Xl (x splits dead once Q/K/V GEMMs are done). ~118 MB.
    unsigned short* Xh = (unsigned short*)d_ws;
    unsigned short* Xl = Xh + MD;
    unsigned short* Wh = Xl + MD;
    unsigned short* Wl = Wh + DD;
    unsigned short* Qh = Wl + DD;
    unsigned short* Ql = Qh + MD;
    unsigned short* Kh = Ql + MD;
    unsigned short* Vh = Kh + MD;
    float* Fc = (float*)(Vh + MD);
    unsigned short* Oh = Xh;   // alias
    unsigned short* Ol = Xl;   // alias

    const dim3 blk(256);
    const dim3 ggrid((M / GBM) * (D / GBN));                 // 512
    const int nMD = (int)MD, nDD = (int)DD;
    const dim3 gsx(nMD / 8 / 256), gsw(nDD / 8 / 256);

    split_kernel<<<gsx, blk, 0, stream>>>(x, Xh, Xl, nMD);
    split_kernel<<<gsw, blk, 0, stream>>>(Wq, Wh, Wl, nDD);
    gemm_pre<<<ggrid, blk, 0, stream>>>(Xh, Xl, Wh, Wl, nullptr, Qh, Ql, D, D);
    split_kernel<<<gsw, blk, 0, stream>>>(Wk, Wh, Wl, nDD);
    gemm_pre<<<ggrid, blk, 0, stream>>>(Xh, Xl, Wh, Wl, nullptr, Kh, nullptr, D, D);
    split_kernel<<<gsw, blk, 0, stream>>>(Wv, Wh, Wl, nDD);
    gemm_pre<<<ggrid, blk, 0, stream>>>(Xh, Xl, Wh, Wl, nullptr, Vh, nullptr, D, D);
    fgate_kernel<<<dim3(M), blk, 0, stream>>>(x, Wf, bf, Fc);
    cumsum_kernel<<<dim3(B * H), blk, 0, stream>>>(Fc);
    attn_mfma2<<<dim3(S / QBLK, 1, B * H), blk, 0, stream>>>(Qh, Ql, Kh, Vh, Fc, Oh, Ol);
    split_kernel<<<gsw, blk, 0, stream>>>(Wo, Wh, Wl, nDD);
    gemm_pre<<<ggrid, blk, 0, stream>>>(Oh, Ol, Wh, Wl, out, nullptr, nullptr, D, D);
}

// Round 9
// 898.322 us; speedup vs baseline: 1.0935x; 1.0935x over previous
//
#include <hip/hip_runtime.h>
#include <math.h>

#define B 2
#define S 2048
#define D 2048
#define H 32
#define HD 64
#define M (B*S)

typedef short s16x8 __attribute__((ext_vector_type(8)));
typedef float f32x4 __attribute__((ext_vector_type(4)));

// fp32 -> bf16 (RNE) and back, pure bit ops
__device__ __forceinline__ unsigned short f2bf(float f) {
    unsigned u = __float_as_uint(f);
    return (unsigned short)((u + 0x7fffu + ((u >> 16) & 1u)) >> 16);
}
__device__ __forceinline__ float bf2f(unsigned short h) {
    return __uint_as_float(((unsigned)h) << 16);
}

// ---------------------------------------------------------------------------
// split: fp32 array -> hi/lo bf16 arrays
// ---------------------------------------------------------------------------
__global__ __launch_bounds__(256) void split_kernel(
    const float* __restrict__ in, unsigned short* __restrict__ hi,
    unsigned short* __restrict__ lo, int n)
{
    const int idx = (blockIdx.x * 256 + threadIdx.x) * 8;
    if (idx >= n) return;
    float f[8];
    *(float4*)&f[0] = *(const float4*)(in + idx);
    *(float4*)&f[4] = *(const float4*)(in + idx + 4);
    unsigned short h[8], l[8];
    #pragma unroll
    for (int e = 0; e < 8; ++e) {
        h[e] = f2bf(f[e]);
        l[e] = f2bf(f[e] - bf2f(h[e]));
    }
    *(s16x8*)&hi[idx] = *(s16x8*)&h[0];
    *(s16x8*)&lo[idx] = *(s16x8*)&l[0];
}

// ---------------------------------------------------------------------------
// bf16x3 MFMA GEMM on PRE-SPLIT inputs (unchanged from round 8, verified)
// ---------------------------------------------------------------------------
#define GBM 128
#define GBN 128
#define GBK 32
#define GLD (GBK + 8)

__global__ __launch_bounds__(256) void gemm_pre(
    const unsigned short* __restrict__ Agh, const unsigned short* __restrict__ Agl,
    const unsigned short* __restrict__ Bgh, const unsigned short* __restrict__ Bgl,
    float* __restrict__ Cf, unsigned short* __restrict__ Ch,
    unsigned short* __restrict__ Cl, int Ndim, int Kdim)
{
    __shared__ unsigned short Ah[GBM * GLD], Al[GBM * GLD];
    __shared__ unsigned short Bh[GBN * GLD], Bl[GBN * GLD];
    const int tid = threadIdx.x;
    const int nwg = gridDim.x, cpx = nwg >> 3;
    const int wg = (blockIdx.x & 7) * cpx + (blockIdx.x >> 3);
    const int ntn = Ndim / GBN;
    const int m0 = (wg / ntn) * GBM, n0 = (wg % ntn) * GBN;

    const int row = tid >> 1;            // 0..127
    const int seg = (tid & 1) << 4;      // 0 or 16 shorts
    const size_t abase = (size_t)(m0 + row) * Kdim + seg;
    const size_t bbase = (size_t)(n0 + row) * Kdim + seg;
    const int sbase = row * GLD + seg;

    const int wv = tid >> 6, lane = tid & 63;
    const int wr = (wv >> 1) << 6, wc = (wv & 1) << 6;
    const int fr = lane & 15, ko = (lane >> 4) << 3;

    f32x4 acc[4][4] = {};
    for (int k0 = 0; k0 < Kdim; k0 += GBK) {
        *(s16x8*)&Ah[sbase]     = *(const s16x8*)&Agh[abase + k0];
        *(s16x8*)&Ah[sbase + 8] = *(const s16x8*)&Agh[abase + k0 + 8];
        *(s16x8*)&Al[sbase]     = *(const s16x8*)&Agl[abase + k0];
        *(s16x8*)&Al[sbase + 8] = *(const s16x8*)&Agl[abase + k0 + 8];
        *(s16x8*)&Bh[sbase]     = *(const s16x8*)&Bgh[bbase + k0];
        *(s16x8*)&Bh[sbase + 8] = *(const s16x8*)&Bgh[bbase + k0 + 8];
        *(s16x8*)&Bl[sbase]     = *(const s16x8*)&Bgl[bbase + k0];
        *(s16x8*)&Bl[sbase + 8] = *(const s16x8*)&Bgl[bbase + k0 + 8];
        __syncthreads();
        s16x8 fah[4], fal[4], fbh[4], fbl[4];
        #pragma unroll
        for (int m = 0; m < 4; ++m) {
            const int r = (wr + m * 16 + fr) * GLD + ko;
            fah[m] = *(s16x8*)&Ah[r];
            fal[m] = *(s16x8*)&Al[r];
        }
        #pragma unroll
        for (int n = 0; n < 4; ++n) {
            const int r = (wc + n * 16 + fr) * GLD + ko;
            fbh[n] = *(s16x8*)&Bh[r];
            fbl[n] = *(s16x8*)&Bl[r];
        }
        #pragma unroll
        for (int m = 0; m < 4; ++m)
            #pragma unroll
            for (int n = 0; n < 4; ++n) {
                acc[m][n] = __builtin_amdgcn_mfma_f32_16x16x32_bf16(fah[m], fbh[n], acc[m][n], 0, 0, 0);
                acc[m][n] = __builtin_amdgcn_mfma_f32_16x16x32_bf16(fah[m], fbl[n], acc[m][n], 0, 0, 0);
                acc[m][n] = __builtin_amdgcn_mfma_f32_16x16x32_bf16(fal[m], fbh[n], acc[m][n], 0, 0, 0);
            }
        __syncthreads();
    }
    const int crow0 = m0 + wr + ((lane >> 4) << 2);
    const int ccol0 = n0 + wc + fr;
    #pragma unroll
    for (int m = 0; m < 4; ++m)
        #pragma unroll
        for (int n = 0; n < 4; ++n)
            #pragma unroll
            for (int r = 0; r < 4; ++r) {
                const float c = acc[m][n][r];
                const size_t idx = (size_t)(crow0 + m * 16 + r) * Ndim + ccol0 + n * 16;
                if (Cf) Cf[idx] = c;
                if (Ch) {
                    const unsigned short hh = f2bf(c);
                    Ch[idx] = hh;
                    if (Cl) Cl[idx] = f2bf(c - bf2f(hh));
                }
            }
}

// ---------------------------------------------------------------------------
// Forget gates (unchanged) + cumsum now writing TRANSPOSED Ct[b,h,s]
// ---------------------------------------------------------------------------
__global__ __launch_bounds__(256) void fgate_kernel(
    const float* __restrict__ x, const float* __restrict__ Wf,
    const float* __restrict__ bfv, float* __restrict__ F)
{
    __shared__ float xs[D];
    const int bs = blockIdx.x;
    const float* xr = x + (size_t)bs * D;
    for (int i = threadIdx.x * 4; i < D; i += 256 * 4)
        *(float4*)&xs[i] = *(const float4*)&xr[i];
    __syncthreads();
    const int wave = threadIdx.x >> 6, lane = threadIdx.x & 63;
    for (int h = wave * 8; h < wave * 8 + 8; ++h) {
        const float* wr = Wf + (size_t)h * D;
        float sum = 0.f;
        for (int i = lane * 4; i < D; i += 64 * 4) {
            float4 w4 = *(const float4*)&wr[i];
            sum += xs[i]*w4.x + xs[i+1]*w4.y + xs[i+2]*w4.z + xs[i+3]*w4.w;
        }
        #pragma unroll
        for (int off = 32; off > 0; off >>= 1) sum += __shfl_down(sum, off);
        if (lane == 0) {
            float z = sum + bfv[h];
            F[(size_t)bs * H + h] = fminf(z, 0.f) - log1pf(expf(-fabsf(z)));
        }
    }
}

__global__ __launch_bounds__(256) void cumsum_kernel(
    const float* __restrict__ F, float* __restrict__ Ct)
{
    const int b = blockIdx.x >> 5;
    const int h = blockIdx.x & 31;
    const float* base = F + (size_t)b * S * H + h;
    float* outb = Ct + (size_t)(b * H + h) * S;
    __shared__ float part[256];
    const int t = threadIdx.x;
    float v[8];
    float run = 0.f;
    #pragma unroll
    for (int i = 0; i < 8; ++i) {
        v[i] = base[(size_t)(t * 8 + i) * H];
        run += v[i];
        v[i] = run;
    }
    part[t] = run;
    __syncthreads();
    for (int off = 1; off < 256; off <<= 1) {
        float add = (t >= off) ? part[t - off] : 0.f;
        __syncthreads();
        part[t] += add;
        __syncthreads();
    }
    const float offs = (t > 0) ? part[t - 1] : 0.f;
    #pragma unroll
    for (int i = 0; i < 8; ++i)
        outb[t * 8 + i] = v[i] + offs;
}

// ---------------------------------------------------------------------------
// MFMA flash attention v3: QBLK=256, 8 waves x 32 q-rows, bf16 inputs.
// - K/V re-read traffic halved vs v2 (QBLK 128->256)
// - O epilogue bounces through per-wave LDS -> vectorized 16B stores
// - cj reads coalesced from transposed Ct
// LDS = 37.4 KB; per-wave P buffer (16 rows) used for PV per m-half + epilogue.
// ---------------------------------------------------------------------------
#define QBLK 256
#define NW 8
#define KV 64
#define PLD 72
#define SCALE 0.125f    // 1/sqrt(64)

__global__ __launch_bounds__(512) void attn_mfma3(
    const unsigned short* __restrict__ Qh, const unsigned short* __restrict__ Ql,
    const unsigned short* __restrict__ Kh, const unsigned short* __restrict__ Vh,
    const float* __restrict__ Ct,
    unsigned short* __restrict__ Oh, unsigned short* __restrict__ Ol)
{
    __shared__ unsigned short Ks[KV * PLD];       // 9.2 KB
    __shared__ unsigned short Vt[HD * PLD];       // 9.2 KB
    __shared__ unsigned short Pb[NW * 16 * PLD];  // 18.4 KB (per-wave 16 rows)
    __shared__ float cj[KV];

    const int qt = (int)gridDim.x - 1 - blockIdx.x;   // LPT: big tiles first
    const int b = blockIdx.z >> 5, h = blockIdx.z & 31;
    const int q0 = qt * QBLK;
    const int tid = threadIdx.x, wv = tid >> 6, lane = tid & 63;
    const int g = lane >> 4, fr = lane & 15;

    // ---- Q fragments: direct global -> registers (once) ----
    s16x8 qfh[2][2], qfl[2][2];   // [m][kd]
    {
        const size_t qb = (size_t)(b * S + q0 + wv * 32) * D + h * HD;
        #pragma unroll
        for (int m = 0; m < 2; ++m)
            #pragma unroll
            for (int kd = 0; kd < 2; ++kd) {
                const size_t off = qb + (size_t)(m * 16 + fr) * D + kd * 32 + g * 8;
                qfh[m][kd] = *(const s16x8*)&Qh[off];
                qfl[m][kd] = *(const s16x8*)&Ql[off];
            }
    }

    f32x4 Oa[2][4] = {};
    float mr[2][4], lr[2][4];
    #pragma unroll
    for (int m = 0; m < 2; ++m)
        #pragma unroll
        for (int r = 0; r < 4; ++r) { mr[m][r] = -INFINITY; lr[m][r] = 0.f; }

    const int imax = q0 + wv * 32 + 31;
    const int nj = (q0 + QBLK) / KV;
    unsigned short* Pw = &Pb[wv * 16 * PLD];

    for (int jt = 0; jt < nj; ++jt) {
        const int j0 = jt * KV;
        // ---- stage K (row-major) + V (transposed); 512 threads, 1 row/8 thr
        {
            const int row = tid >> 3;            // 0..63 (j)
            const int seg = (tid & 7) << 3;      // 0..56 step 8 (shorts)
            const size_t goff = (size_t)(b * S + j0 + row) * D + h * HD + seg;
            *(s16x8*)&Ks[row * PLD + seg] = *(const s16x8*)&Kh[goff];
            s16x8 v0 = *(const s16x8*)&Vh[goff];
            #pragma unroll
            for (int e = 0; e < 8; ++e)
                Vt[(seg + e) * PLD + row] = (unsigned short)v0[e];
            if (tid < KV)
                cj[tid] = Ct[(size_t)(b * H + h) * S + j0 + tid];  // coalesced
        }
        __syncthreads();

        if (j0 <= imax) {
            // ---- QK^T (hi + lo) ----
            s16x8 kfr[4][2];
            #pragma unroll
            for (int n = 0; n < 4; ++n)
                #pragma unroll
                for (int kd = 0; kd < 2; ++kd)
                    kfr[n][kd] = *(s16x8*)&Ks[(n * 16 + fr) * PLD + kd * 32 + g * 8];
            f32x4 sa[2][4] = {};
            #pragma unroll
            for (int m = 0; m < 2; ++m)
                #pragma unroll
                for (int n = 0; n < 4; ++n) {
                    #pragma unroll
                    for (int kd = 0; kd < 2; ++kd) {
                        sa[m][n] = __builtin_amdgcn_mfma_f32_16x16x32_bf16(qfh[m][kd], kfr[n][kd], sa[m][n], 0, 0, 0);
                        sa[m][n] = __builtin_amdgcn_mfma_f32_16x16x32_bf16(qfl[m][kd], kfr[n][kd], sa[m][n], 0, 0, 0);
                    }
                }
            // ---- scores: scale, -c_j, causal mask ----
            float cjr[4];
            #pragma unroll
            for (int n = 0; n < 4; ++n) cjr[n] = cj[fr + 16 * n];
            float sc[2][4][4];
            float tm[2][4];
            #pragma unroll
            for (int m = 0; m < 2; ++m)
                #pragma unroll
                for (int r = 0; r < 4; ++r) tm[m][r] = -INFINITY;
            #pragma unroll
            for (int m = 0; m < 2; ++m)
                #pragma unroll
                for (int n = 0; n < 4; ++n)
                    #pragma unroll
                    for (int r = 0; r < 4; ++r) {
                        const int qrow = q0 + wv * 32 + m * 16 + g * 4 + r;
                        const int jcol = j0 + fr + 16 * n;
                        float s = sa[m][n][r] * SCALE - cjr[n];
                        s = (jcol <= qrow) ? s : -INFINITY;
                        sc[m][n][r] = s;
                        tm[m][r] = fmaxf(tm[m][r], s);
                    }
            #pragma unroll
            for (int m = 0; m < 2; ++m)
                #pragma unroll
                for (int r = 0; r < 4; ++r) {
                    float v = tm[m][r];
                    v = fmaxf(v, __shfl_xor(v, 1));
                    v = fmaxf(v, __shfl_xor(v, 2));
                    v = fmaxf(v, __shfl_xor(v, 4));
                    v = fmaxf(v, __shfl_xor(v, 8));
                    tm[m][r] = v;
                }
            #pragma unroll
            for (int m = 0; m < 2; ++m)
                #pragma unroll
                for (int r = 0; r < 4; ++r) {
                    const float newm = fmaxf(mr[m][r], tm[m][r]);
                    const float corr = __expf(mr[m][r] - newm);   // 0 when -inf
                    mr[m][r] = newm;
                    lr[m][r] *= corr;
                    #pragma unroll
                    for (int n = 0; n < 4; ++n) Oa[m][n][r] *= corr;
                }
            // ---- V fragments (shared across m) ----
            s16x8 vfr[4][2];
            #pragma unroll
            for (int n = 0; n < 4; ++n)
                #pragma unroll
                for (int kj = 0; kj < 2; ++kj)
                    vfr[n][kj] = *(s16x8*)&Vt[(n * 16 + fr) * PLD + kj * 32 + g * 8];
            // ---- per m-half: p = exp(s-m), pack 16 rows to Pw, PV MFMA ----
            #pragma unroll
            for (int m = 0; m < 2; ++m) {
                float ps[4];
                #pragma unroll
                for (int r = 0; r < 4; ++r) ps[r] = 0.f;
                #pragma unroll
                for (int n = 0; n < 4; ++n)
                    #pragma unroll
                    for (int r = 0; r < 4; ++r) {
                        const float p = __expf(sc[m][n][r] - mr[m][r]);
                        ps[r] += p;
                        Pw[(g * 4 + r) * PLD + fr + 16 * n] = f2bf(p);
                    }
                #pragma unroll
                for (int r = 0; r < 4; ++r) {
                    float v = ps[r];
                    v += __shfl_xor(v, 1);
                    v += __shfl_xor(v, 2);
                    v += __shfl_xor(v, 4);
                    v += __shfl_xor(v, 8);
                    lr[m][r] += v;
                }
                s16x8 pf[2];
                #pragma unroll
                for (int kj = 0; kj < 2; ++kj)
                    pf[kj] = *(s16x8*)&Pw[fr * PLD + kj * 32 + g * 8];
                #pragma unroll
                for (int n = 0; n < 4; ++n)
                    #pragma unroll
                    for (int kj = 0; kj < 2; ++kj)
                        Oa[m][n] = __builtin_amdgcn_mfma_f32_16x16x32_bf16(pf[kj], vfr[n][kj], Oa[m][n], 0, 0, 0);
            }
        }
        __syncthreads();
    }

    // ---- epilogue: normalize, bounce via Pw, vectorized 16B stores ----
    #pragma unroll
    for (int m = 0; m < 2; ++m) {
        float inv[4];
        #pragma unroll
        for (int r = 0; r < 4; ++r) inv[r] = 1.f / lr[m][r];
        const int row_l = lane >> 2;                 // 0..15
        const int ch = (lane & 3) << 4;              // 0,16,32,48 shorts
        const size_t grow = (size_t)(b * S + q0 + wv * 32 + m * 16 + row_l) * D + h * HD + ch;
        // hi part
        #pragma unroll
        for (int n = 0; n < 4; ++n)
            #pragma unroll
            for (int r = 0; r < 4; ++r)
                Pw[(g * 4 + r) * PLD + fr + 16 * n] = f2bf(Oa[m][n][r] * inv[r]);
        *(s16x8*)&Oh[grow]     = *(s16x8*)&Pw[row_l * PLD + ch];
        *(s16x8*)&Oh[grow + 8] = *(s16x8*)&Pw[row_l * PLD + ch + 8];
        // lo part (DS ops are in-order within a wave)
        #pragma unroll
        for (int n = 0; n < 4; ++n)
            #pragma unroll
            for (int r = 0; r < 4; ++r) {
                const float c = Oa[m][n][r] * inv[r];
                Pw[(g * 4 + r) * PLD + fr + 16 * n] = f2bf(c - bf2f(f2bf(c)));
            }
        *(s16x8*)&Ol[grow]     = *(s16x8*)&Pw[row_l * PLD + ch];
        *(s16x8*)&Ol[grow + 8] = *(s16x8*)&Pw[row_l * PLD + ch + 8];
    }
}

// ---------------------------------------------------------------------------
extern "C" void kernel_launch(void* const* d_in, const int* in_sizes, int n_in,
                              void* d_out, int out_size, void* d_ws, size_t ws_size,
                              hipStream_t stream) {
    const float* x  = (const float*)d_in[0];
    const float* Wq = (const float*)d_in[1];
    const float* Wk = (const float*)d_in[2];
    const float* Wv = (const float*)d_in[3];
    const float* Wf = (const float*)d_in[4];
    const float* bf = (const float*)d_in[5];
    const float* Wo = (const float*)d_in[6];
    float* out = (float*)d_out;

    const size_t MD = (size_t)M * D, DD = (size_t)D * D;
    // ws layout (shorts): Xh | Xl | Wh | Wl | Qh | Ql | Kh | Vh | Fc | Ct (~136 MB)
    unsigned short* Xh = (unsigned short*)d_ws;
    unsigned short* Xl = Xh + MD;
    unsigned short* Wh = Xl + MD;
    unsigned short* Wl = Wh + DD;
    unsigned short* Qh = Wl + DD;
    unsigned short* Ql = Qh + MD;
    unsigned short* Kh = Ql + MD;
    unsigned short* Vh = Kh + MD;
    float* Fc = (float*)(Vh + MD);
    float* Ct = Fc + (size_t)M * H;
    unsigned short* Oh = Xh;   // alias (x splits dead after V GEMM)
    unsigned short* Ol = Xl;   // alias

    const dim3 blk(256);
    const dim3 ggrid((M / GBM) * (D / GBN));                 // 512
    const int nMD = (int)MD, nDD = (int)DD;
    const dim3 gsx(nMD / 8 / 256), gsw(nDD / 8 / 256);

    split_kernel<<<gsx, blk, 0, stream>>>(x, Xh, Xl, nMD);
    split_kernel<<<gsw, blk, 0, stream>>>(Wq, Wh, Wl, nDD);
    gemm_pre<<<ggrid, blk, 0, stream>>>(Xh, Xl, Wh, Wl, nullptr, Qh, Ql, D, D);
    split_kernel<<<gsw, blk, 0, stream>>>(Wk, Wh, Wl, nDD);
    gemm_pre<<<ggrid, blk, 0, stream>>>(Xh, Xl, Wh, Wl, nullptr, Kh, nullptr, D, D);
    split_kernel<<<gsw, blk, 0, stream>>>(Wv, Wh, Wl, nDD);
    gemm_pre<<<ggrid, blk, 0, stream>>>(Xh, Xl, Wh, Wl, nullptr, Vh, nullptr, D, D);
    fgate_kernel<<<dim3(M), blk, 0, stream>>>(x, Wf, bf, Fc);
    cumsum_kernel<<<dim3(B * H), blk, 0, stream>>>(Fc, Ct);
    attn_mfma3<<<dim3(S / QBLK, 1, B * H), dim3(512), 0, stream>>>(Qh, Ql, Kh, Vh, Ct, Oh, Ol);
    split_kernel<<<gsw, blk, 0, stream>>>(Wo, Wh, Wl, nDD);
    gemm_pre<<<ggrid, blk, 0, stream>>>(Oh, Ol, Wh, Wl, out, nullptr, nullptr, D, D);
}

// Round 11
// 822.012 us; speedup vs baseline: 1.1950x; 1.0928x over previous
//
#include <hip/hip_runtime.h>
#include <math.h>

#define B 2
#define S 2048
#define D 2048
#define H 32
#define HD 64
#define M (B*S)
#define MH ((size_t)M * H)

typedef short s16x8 __attribute__((ext_vector_type(8)));
typedef float f32x4 __attribute__((ext_vector_type(4)));

__device__ __forceinline__ unsigned short f2bf(float f) {
    unsigned u = __float_as_uint(f);
    return (unsigned short)((u + 0x7fffu + ((u >> 16) & 1u)) >> 16);
}
__device__ __forceinline__ float bf2f(unsigned short h) {
    return __uint_as_float(((unsigned)h) << 16);
}

// ---------------------------------------------------------------------------
// split: fp32 -> hi bf16 (+ optional lo)
// ---------------------------------------------------------------------------
__global__ __launch_bounds__(256) void split_kernel(
    const float* __restrict__ in, unsigned short* __restrict__ hi,
    unsigned short* __restrict__ lo, int n)
{
    const int idx = (blockIdx.x * 256 + threadIdx.x) * 8;
    if (idx >= n) return;
    float f[8];
    *(float4*)&f[0] = *(const float4*)(in + idx);
    *(float4*)&f[4] = *(const float4*)(in + idx + 4);
    unsigned short h[8], l[8];
    #pragma unroll
    for (int e = 0; e < 8; ++e) {
        h[e] = f2bf(f[e]);
        l[e] = f2bf(f[e] - bf2f(h[e]));
    }
    *(s16x8*)&hi[idx] = *(s16x8*)&h[0];
    if (lo) *(s16x8*)&lo[idx] = *(s16x8*)&l[0];
}

// ---------------------------------------------------------------------------
// MFMA GEMM on pre-split inputs. use_lo (Agl!=null): bf16x3; else pure bf16.
// ---------------------------------------------------------------------------
#define GBM 128
#define GBN 128
#define GBK 32
#define GLD (GBK + 8)

__global__ __launch_bounds__(256) void gemm_pre(
    const unsigned short* __restrict__ Agh, const unsigned short* __restrict__ Agl,
    const unsigned short* __restrict__ Bgh, const unsigned short* __restrict__ Bgl,
    float* __restrict__ Cf, unsigned short* __restrict__ Ch,
    unsigned short* __restrict__ Cl, int Ndim, int Kdim)
{
    __shared__ unsigned short Ah[GBM * GLD], Al[GBM * GLD];
    __shared__ unsigned short Bh[GBN * GLD], Bl[GBN * GLD];
    const bool ulo = (Agl != nullptr);
    const int tid = threadIdx.x;
    const int nwg = gridDim.x, cpx = nwg >> 3;
    const int wg = (blockIdx.x & 7) * cpx + (blockIdx.x >> 3);
    const int ntn = Ndim / GBN;
    const int m0 = (wg / ntn) * GBM, n0 = (wg % ntn) * GBN;

    const int row = tid >> 1;
    const int seg = (tid & 1) << 4;
    const size_t abase = (size_t)(m0 + row) * Kdim + seg;
    const size_t bbase = (size_t)(n0 + row) * Kdim + seg;
    const int sbase = row * GLD + seg;

    const int wv = tid >> 6, lane = tid & 63;
    const int wr = (wv >> 1) << 6, wc = (wv & 1) << 6;
    const int fr = lane & 15, ko = (lane >> 4) << 3;

    f32x4 acc[4][4] = {};
    for (int k0 = 0; k0 < Kdim; k0 += GBK) {
        *(s16x8*)&Ah[sbase]     = *(const s16x8*)&Agh[abase + k0];
        *(s16x8*)&Ah[sbase + 8] = *(const s16x8*)&Agh[abase + k0 + 8];
        *(s16x8*)&Bh[sbase]     = *(const s16x8*)&Bgh[bbase + k0];
        *(s16x8*)&Bh[sbase + 8] = *(const s16x8*)&Bgh[bbase + k0 + 8];
        if (ulo) {
            *(s16x8*)&Al[sbase]     = *(const s16x8*)&Agl[abase + k0];
            *(s16x8*)&Al[sbase + 8] = *(const s16x8*)&Agl[abase + k0 + 8];
            *(s16x8*)&Bl[sbase]     = *(const s16x8*)&Bgl[bbase + k0];
            *(s16x8*)&Bl[sbase + 8] = *(const s16x8*)&Bgl[bbase + k0 + 8];
        }
        __syncthreads();
        s16x8 fah[4], fal[4], fbh[4], fbl[4];
        #pragma unroll
        for (int m = 0; m < 4; ++m) {
            const int r = (wr + m * 16 + fr) * GLD + ko;
            fah[m] = *(s16x8*)&Ah[r];
            if (ulo) fal[m] = *(s16x8*)&Al[r];
        }
        #pragma unroll
        for (int n = 0; n < 4; ++n) {
            const int r = (wc + n * 16 + fr) * GLD + ko;
            fbh[n] = *(s16x8*)&Bh[r];
            if (ulo) fbl[n] = *(s16x8*)&Bl[r];
        }
        #pragma unroll
        for (int m = 0; m < 4; ++m)
            #pragma unroll
            for (int n = 0; n < 4; ++n) {
                acc[m][n] = __builtin_amdgcn_mfma_f32_16x16x32_bf16(fah[m], fbh[n], acc[m][n], 0, 0, 0);
                if (ulo) {
                    acc[m][n] = __builtin_amdgcn_mfma_f32_16x16x32_bf16(fah[m], fbl[n], acc[m][n], 0, 0, 0);
                    acc[m][n] = __builtin_amdgcn_mfma_f32_16x16x32_bf16(fal[m], fbh[n], acc[m][n], 0, 0, 0);
                }
            }
        __syncthreads();
    }
    const int crow0 = m0 + wr + ((lane >> 4) << 2);
    const int ccol0 = n0 + wc + fr;
    #pragma unroll
    for (int m = 0; m < 4; ++m)
        #pragma unroll
        for (int n = 0; n < 4; ++n)
            #pragma unroll
            for (int r = 0; r < 4; ++r) {
                const float c = acc[m][n][r];
                const size_t idx = (size_t)(crow0 + m * 16 + r) * Ndim + ccol0 + n * 16;
                if (Cf) Cf[idx] = c;
                if (Ch) {
                    const unsigned short hh = f2bf(c);
                    Ch[idx] = hh;
                    if (Cl) Cl[idx] = f2bf(c - bf2f(hh));
                }
            }
}

// ---------------------------------------------------------------------------
// Forget gates + cumsum (transposed out) — unchanged, verified
// ---------------------------------------------------------------------------
__global__ __launch_bounds__(256) void fgate_kernel(
    const float* __restrict__ x, const float* __restrict__ Wf,
    const float* __restrict__ bfv, float* __restrict__ F)
{
    __shared__ float xs[D];
    const int bs = blockIdx.x;
    const float* xr = x + (size_t)bs * D;
    for (int i = threadIdx.x * 4; i < D; i += 256 * 4)
        *(float4*)&xs[i] = *(const float4*)&xr[i];
    __syncthreads();
    const int wave = threadIdx.x >> 6, lane = threadIdx.x & 63;
    for (int h = wave * 8; h < wave * 8 + 8; ++h) {
        const float* wr = Wf + (size_t)h * D;
        float sum = 0.f;
        for (int i = lane * 4; i < D; i += 64 * 4) {
            float4 w4 = *(const float4*)&wr[i];
            sum += xs[i]*w4.x + xs[i+1]*w4.y + xs[i+2]*w4.z + xs[i+3]*w4.w;
        }
        #pragma unroll
        for (int off = 32; off > 0; off >>= 1) sum += __shfl_down(sum, off);
        if (lane == 0) {
            float z = sum + bfv[h];
            F[(size_t)bs * H + h] = fminf(z, 0.f) - log1pf(expf(-fabsf(z)));
        }
    }
}

__global__ __launch_bounds__(256) void cumsum_kernel(
    const float* __restrict__ F, float* __restrict__ Ct)
{
    const int b = blockIdx.x >> 5;
    const int h = blockIdx.x & 31;
    const float* base = F + (size_t)b * S * H + h;
    float* outb = Ct + (size_t)(b * H + h) * S;
    __shared__ float part[256];
    const int t = threadIdx.x;
    float v[8];
    float run = 0.f;
    #pragma unroll
    for (int i = 0; i < 8; ++i) {
        v[i] = base[(size_t)(t * 8 + i) * H];
        run += v[i];
        v[i] = run;
    }
    part[t] = run;
    __syncthreads();
    for (int off = 1; off < 256; off <<= 1) {
        float add = (t >= off) ? part[t - off] : 0.f;
        __syncthreads();
        part[t] += add;
        __syncthreads();
    }
    const float offs = (t > 0) ? part[t - 1] : 0.f;
    #pragma unroll
    for (int i = 0; i < 8; ++i)
        outb[t * 8 + i] = v[i] + offs;
}

// ---------------------------------------------------------------------------
// MFMA flash attention v4: QBLK=256, 8 waves; Q hi-only (16 QK MFMA/iter);
// split-j x2 (blockIdx.y): each half writes UNNORMALIZED O partials (hi/lo)
// + per-row (m,l). merge_kernel combines + normalizes.
// ---------------------------------------------------------------------------
#define QBLK 256
#define NTILES (S / QBLK)
#define NW 8
#define KV 64
#define PLD 72
#define SCALE 0.125f

__global__ __launch_bounds__(512) void attn_mfma4(
    const unsigned short* __restrict__ Qh,
    const unsigned short* __restrict__ Kh, const unsigned short* __restrict__ Vh,
    const float* __restrict__ Ct,
    unsigned short* __restrict__ P0h, unsigned short* __restrict__ P0l,
    unsigned short* __restrict__ P1h, unsigned short* __restrict__ P1l,
    float* __restrict__ ML)
{
    __shared__ unsigned short Ks[KV * PLD];
    __shared__ unsigned short Vt[HD * PLD];
    __shared__ unsigned short Pb[NW * 16 * PLD];
    __shared__ float cj[KV];

    const int qt = NTILES - 1 - (int)blockIdx.x;   // LPT: big tiles first
    const int sp = blockIdx.y;
    const int b = blockIdx.z >> 5, h = blockIdx.z & 31;
    const int q0 = qt * QBLK;
    const int tid = threadIdx.x, wv = tid >> 6, lane = tid & 63;
    const int g = lane >> 4, fr = lane & 15;
    unsigned short* Oph = sp ? P1h : P0h;
    unsigned short* Opl = sp ? P1l : P0l;
    float* MLp = ML + (size_t)sp * MH * 2;

    // ---- Q fragments (hi only): direct global -> registers ----
    s16x8 qfh[2][2];
    {
        const size_t qb = (size_t)(b * S + q0 + wv * 32) * D + h * HD;
        #pragma unroll
        for (int m = 0; m < 2; ++m)
            #pragma unroll
            for (int kd = 0; kd < 2; ++kd)
                qfh[m][kd] = *(const s16x8*)&Qh[qb + (size_t)(m * 16 + fr) * D + kd * 32 + g * 8];
    }

    f32x4 Oa[2][4] = {};
    float mr[2][4], lr[2][4];
    #pragma unroll
    for (int m = 0; m < 2; ++m)
        #pragma unroll
        for (int r = 0; r < 4; ++r) { mr[m][r] = -INFINITY; lr[m][r] = 0.f; }

    const int imax = q0 + wv * 32 + 31;
    const int half = (q0 + QBLK) / KV / 2;     // nj = 4qt+4, divisible by 2
    const int t0 = sp * half, t1 = t0 + half;
    unsigned short* Pw = &Pb[wv * 16 * PLD];

    for (int jt = t0; jt < t1; ++jt) {
        const int j0 = jt * KV;
        {
            const int row = tid >> 3;
            const int seg = (tid & 7) << 3;
            const size_t goff = (size_t)(b * S + j0 + row) * D + h * HD + seg;
            *(s16x8*)&Ks[row * PLD + seg] = *(const s16x8*)&Kh[goff];
            s16x8 v0 = *(const s16x8*)&Vh[goff];
            #pragma unroll
            for (int e = 0; e < 8; ++e)
                Vt[(seg + e) * PLD + row] = (unsigned short)v0[e];
            if (tid < KV)
                cj[tid] = Ct[(size_t)(b * H + h) * S + j0 + tid];
        }
        __syncthreads();

        if (j0 <= imax) {
            s16x8 kfr[4][2];
            #pragma unroll
            for (int n = 0; n < 4; ++n)
                #pragma unroll
                for (int kd = 0; kd < 2; ++kd)
                    kfr[n][kd] = *(s16x8*)&Ks[(n * 16 + fr) * PLD + kd * 32 + g * 8];
            f32x4 sa[2][4] = {};
            #pragma unroll
            for (int m = 0; m < 2; ++m)
                #pragma unroll
                for (int n = 0; n < 4; ++n)
                    #pragma unroll
                    for (int kd = 0; kd < 2; ++kd)
                        sa[m][n] = __builtin_amdgcn_mfma_f32_16x16x32_bf16(qfh[m][kd], kfr[n][kd], sa[m][n], 0, 0, 0);
            float cjr[4];
            #pragma unroll
            for (int n = 0; n < 4; ++n) cjr[n] = cj[fr + 16 * n];
            float sc[2][4][4];
            float tm[2][4];
            #pragma unroll
            for (int m = 0; m < 2; ++m)
                #pragma unroll
                for (int r = 0; r < 4; ++r) tm[m][r] = -INFINITY;
            #pragma unroll
            for (int m = 0; m < 2; ++m)
                #pragma unroll
                for (int n = 0; n < 4; ++n)
                    #pragma unroll
                    for (int r = 0; r < 4; ++r) {
                        const int qrow = q0 + wv * 32 + m * 16 + g * 4 + r;
                        const int jcol = j0 + fr + 16 * n;
                        float s = sa[m][n][r] * SCALE - cjr[n];
                        s = (jcol <= qrow) ? s : -INFINITY;
                        sc[m][n][r] = s;
                        tm[m][r] = fmaxf(tm[m][r], s);
                    }
            #pragma unroll
            for (int m = 0; m < 2; ++m)
                #pragma unroll
                for (int r = 0; r < 4; ++r) {
                    float v = tm[m][r];
                    v = fmaxf(v, __shfl_xor(v, 1));
                    v = fmaxf(v, __shfl_xor(v, 2));
                    v = fmaxf(v, __shfl_xor(v, 4));
                    v = fmaxf(v, __shfl_xor(v, 8));
                    tm[m][r] = v;
                }
            #pragma unroll
            for (int m = 0; m < 2; ++m)
                #pragma unroll
                for (int r = 0; r < 4; ++r) {
                    const float newm = fmaxf(mr[m][r], tm[m][r]);
                    const float corr = __expf(mr[m][r] - newm);   // 0 when -inf
                    mr[m][r] = newm;
                    lr[m][r] *= corr;
                    #pragma unroll
                    for (int n = 0; n < 4; ++n) Oa[m][n][r] *= corr;
                }
            s16x8 vfr[4][2];
            #pragma unroll
            for (int n = 0; n < 4; ++n)
                #pragma unroll
                for (int kj = 0; kj < 2; ++kj)
                    vfr[n][kj] = *(s16x8*)&Vt[(n * 16 + fr) * PLD + kj * 32 + g * 8];
            #pragma unroll
            for (int m = 0; m < 2; ++m) {
                float ps[4];
                #pragma unroll
                for (int r = 0; r < 4; ++r) ps[r] = 0.f;
                #pragma unroll
                for (int n = 0; n < 4; ++n)
                    #pragma unroll
                    for (int r = 0; r < 4; ++r) {
                        const float p = __expf(sc[m][n][r] - mr[m][r]);
                        ps[r] += p;
                        Pw[(g * 4 + r) * PLD + fr + 16 * n] = f2bf(p);
                    }
                #pragma unroll
                for (int r = 0; r < 4; ++r) {
                    float v = ps[r];
                    v += __shfl_xor(v, 1);
                    v += __shfl_xor(v, 2);
                    v += __shfl_xor(v, 4);
                    v += __shfl_xor(v, 8);
                    lr[m][r] += v;
                }
                s16x8 pf[2];
                #pragma unroll
                for (int kj = 0; kj < 2; ++kj)
                    pf[kj] = *(s16x8*)&Pw[fr * PLD + kj * 32 + g * 8];
                #pragma unroll
                for (int n = 0; n < 4; ++n)
                    #pragma unroll
                    for (int kj = 0; kj < 2; ++kj)
                        Oa[m][n] = __builtin_amdgcn_mfma_f32_16x16x32_bf16(pf[kj], vfr[n][kj], Oa[m][n], 0, 0, 0);
            }
        }
        __syncthreads();
    }

    // ---- epilogue: UNNORMALIZED partials (hi/lo) + (m,l) per row ----
    #pragma unroll
    for (int m = 0; m < 2; ++m) {
        const int row_l = lane >> 2;
        const int ch = (lane & 3) << 4;
        const size_t grow = (size_t)(b * S + q0 + wv * 32 + m * 16 + row_l) * D + h * HD + ch;
        #pragma unroll
        for (int n = 0; n < 4; ++n)
            #pragma unroll
            for (int r = 0; r < 4; ++r)
                Pw[(g * 4 + r) * PLD + fr + 16 * n] = f2bf(Oa[m][n][r]);
        *(s16x8*)&Oph[grow]     = *(s16x8*)&Pw[row_l * PLD + ch];
        *(s16x8*)&Oph[grow + 8] = *(s16x8*)&Pw[row_l * PLD + ch + 8];
        #pragma unroll
        for (int n = 0; n < 4; ++n)
            #pragma unroll
            for (int r = 0; r < 4; ++r) {
                const float c = Oa[m][n][r];
                Pw[(g * 4 + r) * PLD + fr + 16 * n] = f2bf(c - bf2f(f2bf(c)));
            }
        *(s16x8*)&Opl[grow]     = *(s16x8*)&Pw[row_l * PLD + ch];
        *(s16x8*)&Opl[grow + 8] = *(s16x8*)&Pw[row_l * PLD + ch + 8];
        if (fr == 0)
            #pragma unroll
            for (int r = 0; r < 4; ++r) {
                const size_t row = (size_t)(b * S + q0 + wv * 32 + m * 16 + g * 4 + r);
                MLp[(row * H + h) * 2]     = mr[m][r];
                MLp[(row * H + h) * 2 + 1] = lr[m][r];
            }
    }
}

// ---------------------------------------------------------------------------
// merge: out = (w0*O0 + w1*O1) / (w0*l0 + w1*l1), written into P0h/P0l
// ---------------------------------------------------------------------------
__global__ __launch_bounds__(256) void merge_kernel(
    unsigned short* __restrict__ P0h, unsigned short* __restrict__ P0l,
    const unsigned short* __restrict__ P1h, const unsigned short* __restrict__ P1l,
    const float* __restrict__ ML)
{
    const size_t t8 = ((size_t)blockIdx.x * 256 + threadIdx.x) * 8;
    const size_t r = t8 / D;
    const int h = (int)((t8 % D) / HD);
    const size_t mlb = (r * H + h) * 2;
    const float m0 = ML[mlb],            l0 = ML[mlb + 1];
    const float m1 = ML[MH * 2 + mlb],   l1 = ML[MH * 2 + mlb + 1];
    const float mx = fmaxf(m0, m1);
    const float w0 = __expf(m0 - mx), w1 = __expf(m1 - mx);
    const float inv = 1.f / (w0 * l0 + w1 * l1);
    s16x8 a0 = *(const s16x8*)&P0h[t8], b0 = *(const s16x8*)&P0l[t8];
    s16x8 a1 = *(const s16x8*)&P1h[t8], b1 = *(const s16x8*)&P1l[t8];
    unsigned short oh[8], ol[8];
    #pragma unroll
    for (int e = 0; e < 8; ++e) {
        const float v0 = bf2f((unsigned short)a0[e]) + bf2f((unsigned short)b0[e]);
        const float v1 = bf2f((unsigned short)a1[e]) + bf2f((unsigned short)b1[e]);
        const float o = (w0 * v0 + w1 * v1) * inv;
        oh[e] = f2bf(o);
        ol[e] = f2bf(o - bf2f(oh[e]));
    }
    *(s16x8*)&P0h[t8] = *(s16x8*)&oh[0];
    *(s16x8*)&P0l[t8] = *(s16x8*)&ol[0];
}

// ---------------------------------------------------------------------------
extern "C" void kernel_launch(void* const* d_in, const int* in_sizes, int n_in,
                              void* d_out, int out_size, void* d_ws, size_t ws_size,
                              hipStream_t stream) {
    const float* x  = (const float*)d_in[0];
    const float* Wq = (const float*)d_in[1];
    const float* Wk = (const float*)d_in[2];
    const float* Wv = (const float*)d_in[3];
    const float* Wf = (const float*)d_in[4];
    const float* bf = (const float*)d_in[5];
    const float* Wo = (const float*)d_in[6];
    float* out = (float*)d_out;

    const size_t MD = (size_t)M * D, DD = (size_t)D * D;
    // ws (shorts): Xh | Wh | Wl | Qh | Kh | Vh | Fc | Ct | P0l | P1h | P1l | ML  (~137 MB)
    unsigned short* Xh = (unsigned short*)d_ws;
    unsigned short* Wh = Xh + MD;
    unsigned short* Wl = Wh + DD;
    unsigned short* Qh = Wl + DD;
    unsigned short* Kh = Qh + MD;
    unsigned short* Vh = Kh + MD;
    float* Fc = (float*)(Vh + MD);
    float* Ct = Fc + MH;
    unsigned short* P0l = (unsigned short*)(Ct + MH);
    unsigned short* P1h = P0l + MD;
    unsigned short* P1l = P1h + MD;
    float* ML = (float*)(P1l + MD);
    unsigned short* P0h = Xh;   // alias: x-hi dead after V GEMM

    const dim3 blk(256);
    const dim3 ggrid((M / GBM) * (D / GBN));
    const int nMD = (int)MD, nDD = (int)DD;
    const dim3 gsx(nMD / 8 / 256), gsw(nDD / 8 / 256);

    split_kernel<<<gsx, blk, 0, stream>>>(x, Xh, nullptr, nMD);
    split_kernel<<<gsw, blk, 0, stream>>>(Wq, Wh, nullptr, nDD);
    gemm_pre<<<ggrid, blk, 0, stream>>>(Xh, nullptr, Wh, nullptr, nullptr, Qh, nullptr, D, D);
    split_kernel<<<gsw, blk, 0, stream>>>(Wk, Wh, nullptr, nDD);
    gemm_pre<<<ggrid, blk, 0, stream>>>(Xh, nullptr, Wh, nullptr, nullptr, Kh, nullptr, D, D);
    split_kernel<<<gsw, blk, 0, stream>>>(Wv, Wh, nullptr, nDD);
    gemm_pre<<<ggrid, blk, 0, stream>>>(Xh, nullptr, Wh, nullptr, nullptr, Vh, nullptr, D, D);
    fgate_kernel<<<dim3(M), blk, 0, stream>>>(x, Wf, bf, Fc);
    cumsum_kernel<<<dim3(B * H), blk, 0, stream>>>(Fc, Ct);
    attn_mfma4<<<dim3(NTILES, 2, B * H), dim3(512), 0, stream>>>(Qh, Kh, Vh, Ct, P0h, P0l, P1h, P1l, ML);
    merge_kernel<<<dim3((int)(MD / 8 / 256)), blk, 0, stream>>>(P0h, P0l, P1h, P1l, ML);
    split_kernel<<<gsw, blk, 0, stream>>>(Wo, Wh, Wl, nDD);
    gemm_pre<<<ggrid, blk, 0, stream>>>(P0h, P0l, Wh, Wl, out, nullptr, nullptr, D, D);
}